// Round 3
// baseline (4992.907 us; speedup 1.0000x reference)
//
#include <hip/hip_runtime.h>
#include <hip/hip_bf16.h>
#include <cstddef>

#define THRESH 1e-6f

__device__ __forceinline__ float thrf(float x) { return x > THRESH ? x : 0.0f; }
__device__ __forceinline__ float sigm(float x) { return 1.0f / (1.0f + expf(-x)); }

// ---------------------------------------------------------------------------
// K1: fused embedding MLP.  Each block handles T=4 tokens, 256 threads = 256
// output channels.  a1[e] = thr(W1[tok][e]+b1[e]) is wave-uniform (token and
// e are uniform) -> compiler scalarizes those loads; W2[e*256+o] is the
// coalesced per-lane stream.
//   emb[t][o] = thr( sum_e a1_t[e] * W2[e][o] + b2[o] )
// ---------------------------------------------------------------------------
template <int T>
__global__ __launch_bounds__(256) void k_embed(const int* __restrict__ tok,
                                               const float* __restrict__ W1,
                                               const float* __restrict__ b1,
                                               const float* __restrict__ W2,
                                               const float* __restrict__ b2,
                                               float* __restrict__ emb) {
    const int t0 = blockIdx.x * T;
    const int o  = threadIdx.x;  // 0..255

    const float* rows[T];
#pragma unroll
    for (int i = 0; i < T; ++i)
        rows[i] = W1 + (size_t)tok[t0 + i] * 512;

    float acc[T];
#pragma unroll
    for (int i = 0; i < T; ++i) acc[i] = 0.0f;

#pragma unroll 8
    for (int e = 0; e < 512; ++e) {
        float be = b1[e];
        float w  = W2[(size_t)e * 256 + o];
#pragma unroll
        for (int i = 0; i < T; ++i)
            acc[i] += thrf(rows[i][e] + be) * w;
    }

    float bo = b2[o];
#pragma unroll
    for (int i = 0; i < T; ++i)
        emb[(size_t)(t0 + i) * 256 + o] = thrf(acc[i] + bo);
}

// ---------------------------------------------------------------------------
// K2: one GRU timestep with the input projection fused in.
// grid = 128 blocks x 256 threads; tid = kh*128 + b*4 + jl
//   kh : k-split half (0/1), b : batch row (0..31), jl : local hidden unit
//   j  = blockIdx.x*4 + jl  in [0,512)
// Computes for gates g in {r,z,n} (rows g*512+j of W_ih / W_hh):
//   x_g = emb_t[b] . W_ih[g*512+j]   (K=256, 128 per kh)
//   h_g = h_in[b]  . W_hh[g*512+j]   (K=512, 256 per kh; 0 if first step)
// then r = sig(x_r+b_ih_r + h_r+b_hh_r), z likewise,
//      n = tanh(x_n+b_ih_n + r*(h_n+b_hh_n)),  h' = (1-z)*n + z*h_prev
// ---------------------------------------------------------------------------
__global__ __launch_bounds__(256) void k_gru_step(const float* __restrict__ h_in,
                                                  float* __restrict__ h_out,
                                                  const float* __restrict__ emb_t, // (32,256)
                                                  const float* __restrict__ W_ih,  // (1536,256)
                                                  const float* __restrict__ W_hh,  // (1536,512)
                                                  const float* __restrict__ b_ih,
                                                  const float* __restrict__ b_hh,
                                                  int first) {
    const int tid = threadIdx.x;
    const int kh = tid >> 7;         // 0..1
    const int b  = (tid >> 2) & 31;  // 0..31
    const int jl = tid & 3;          // 0..3
    const int j  = blockIdx.x * 4 + jl;

    // ---- x-projection part (K=256, this thread does 128) ----
    const float* ev  = emb_t + (size_t)b * 256 + kh * 128;
    const float* xwr = W_ih + (size_t)j * 256 + kh * 128;
    const float* xwz = W_ih + (size_t)(512 + j) * 256 + kh * 128;
    const float* xwn = W_ih + (size_t)(1024 + j) * 256 + kh * 128;
    float xr = 0.f, xz = 0.f, xn = 0.f;
#pragma unroll 8
    for (int k = 0; k < 128; k += 4) {
        float4 e4 = *(const float4*)(ev + k);
        float4 r4 = *(const float4*)(xwr + k);
        float4 z4 = *(const float4*)(xwz + k);
        float4 n4 = *(const float4*)(xwn + k);
        xr += e4.x * r4.x + e4.y * r4.y + e4.z * r4.z + e4.w * r4.w;
        xz += e4.x * z4.x + e4.y * z4.y + e4.z * z4.z + e4.w * z4.w;
        xn += e4.x * n4.x + e4.y * n4.y + e4.z * n4.z + e4.w * n4.w;
    }

    // ---- h-projection part (K=512, this thread does 256) ----
    float hr = 0.f, hz = 0.f, hn = 0.f;
    if (!first) {
        const float* hv  = h_in + (size_t)b * 512 + kh * 256;
        const float* hwr = W_hh + (size_t)j * 512 + kh * 256;
        const float* hwz = W_hh + (size_t)(512 + j) * 512 + kh * 256;
        const float* hwn = W_hh + (size_t)(1024 + j) * 512 + kh * 256;
#pragma unroll 8
        for (int k = 0; k < 256; k += 4) {
            float4 h4 = *(const float4*)(hv + k);
            float4 r4 = *(const float4*)(hwr + k);
            float4 z4 = *(const float4*)(hwz + k);
            float4 n4 = *(const float4*)(hwn + k);
            hr += h4.x * r4.x + h4.y * r4.y + h4.z * r4.z + h4.w * r4.w;
            hz += h4.x * z4.x + h4.y * z4.y + h4.z * z4.z + h4.w * z4.w;
            hn += h4.x * n4.x + h4.y * n4.y + h4.z * n4.z + h4.w * n4.w;
        }
    }

    __shared__ float red[128][6];
    if (kh == 1) {
        float* r = red[tid - 128];
        r[0] = xr; r[1] = xz; r[2] = xn;
        r[3] = hr; r[4] = hz; r[5] = hn;
    }
    __syncthreads();

    if (kh == 0) {
        const float* rd = red[tid];
        xr += rd[0]; xz += rd[1]; xn += rd[2];
        hr += rd[3]; hz += rd[4]; hn += rd[5];

        float r = sigm((xr + b_ih[j])        + (hr + b_hh[j]));
        float z = sigm((xz + b_ih[512 + j])  + (hz + b_hh[512 + j]));
        float n = tanhf((xn + b_ih[1024 + j]) + r * (hn + b_hh[1024 + j]));
        float hprev = first ? 0.0f : h_in[(size_t)b * 512 + j];
        h_out[(size_t)b * 512 + j] = (1.0f - z) * n + z * hprev;
    }
}

// ---------------------------------------------------------------------------
// K3: head.  out[b][o] = sum_k h[b][k] * W3[k][o] + b3[o]
// block = batch row (h row is uniform -> scalarized loads), 256 threads = o.
// ---------------------------------------------------------------------------
__global__ __launch_bounds__(256) void k_head(const float* __restrict__ h,
                                              const float* __restrict__ W3,
                                              const float* __restrict__ b3,
                                              float* __restrict__ out) {
    const int b = blockIdx.x;
    const int o = threadIdx.x;
    const float* hrow = h + (size_t)b * 512;
    float acc = b3[o];
#pragma unroll 8
    for (int k = 0; k < 512; ++k)
        acc += hrow[k] * W3[(size_t)k * 256 + o];
    out[(size_t)b * 256 + o] = acc;
}

// ---------------------------------------------------------------------------
extern "C" void kernel_launch(void* const* d_in, const int* in_sizes, int n_in,
                              void* d_out, int out_size, void* d_ws, size_t ws_size,
                              hipStream_t stream) {
    // setup_inputs() dict order:
    //   0:input 1:W1 2:b1 3:W2 4:b2 5:W_ih 6:W_hh 7:b_ih 8:b_hh 9:W3 10:b3
    // (R1/R2 bug: W_hh/b_ih were swapped -> OOB reads of the 1536-elem b_ih
    //  buffer as a 786k-elem matrix -> GPU fault / core dump.)
    const int*   tok  = (const int*)d_in[0];
    const float* W1   = (const float*)d_in[1];
    const float* b1   = (const float*)d_in[2];
    const float* W2   = (const float*)d_in[3];
    const float* b2   = (const float*)d_in[4];
    const float* W_ih = (const float*)d_in[5];
    const float* W_hh = (const float*)d_in[6];
    const float* b_ih = (const float*)d_in[7];
    const float* b_hh = (const float*)d_in[8];
    const float* W3   = (const float*)d_in[9];
    const float* b3   = (const float*)d_in[10];
    float* out = (float*)d_out;

    // workspace layout (floats): total ~4.2 MB
    float* ws  = (float*)d_ws;
    float* emb = ws;                  // 4096*256 = 1,048,576 floats (4 MB)
    float* h_a = ws + 1048576;        // 32*512 = 16384 floats
    float* h_b = h_a + 16384;         // 32*512 = 16384 floats

    // fused embedding MLP: emb = thr(thr(W1[tok]+b1) @ W2 + b2)
    k_embed<4><<<4096 / 4, 256, 0, stream>>>(tok, W1, b1, W2, b2, emb);

    // GRU scan: 128 sequential launches (implicit grid barrier between steps);
    // x-projection fused into each step.
    const float* hin = h_a;  // unused at t=0 (first=1)
    float* hout = h_b;
    for (int t = 0; t < 128; ++t) {
        k_gru_step<<<128, 256, 0, stream>>>(hin, hout, emb + (size_t)t * 32 * 256,
                                            W_ih, W_hh, b_ih, b_hh, t == 0 ? 1 : 0);
        float* tmp = (float*)hin;
        hin = hout;
        hout = tmp;
    }

    // head on final hidden state (pointed to by hin after last swap)
    k_head<<<32, 256, 0, stream>>>(hin, W3, b3, out);
}